// Round 8
// baseline (60003.784 us; speedup 1.0000x reference)
//
#include <hip/hip_runtime.h>
#include <hip/hip_bf16.h>
#include <math.h>

typedef unsigned int u32;
typedef unsigned short u16;

// ---------- bf16 helpers ----------
__device__ __forceinline__ float bfbits(u32 hi) { union { u32 u; float f; } v; v.u = hi; return v.f; }
__device__ __forceinline__ float lo16(u32 p) { return bfbits(p << 16); }
__device__ __forceinline__ float hi16(u32 p) { return bfbits(p & 0xffff0000u); }
__device__ __forceinline__ float b2f(u16 x) { return bfbits(((u32)x) << 16); }
__device__ __forceinline__ u16 f2b(float f) {
    union { float f; u32 u; } v; v.f = f;
    u32 u = v.u;
    u32 r = (u + 0x7fffu + ((u >> 16) & 1u)) >> 16;  // RNE
    return (u16)r;
}
__device__ __forceinline__ float cvtf(float x) { return x; }
__device__ __forceinline__ float cvtf(u16 x) { return b2f(x); }
__device__ __forceinline__ void storef(float* p, float v) { *p = v; }
__device__ __forceinline__ void storef(u16* p, float v) { *p = f2b(v); }
__device__ __forceinline__ float sigf(float x) { return 1.f / (1.f + expf(-x)); }
// dot of one uint4 (8 packed bf16) against 8 floats at p (LDS)
__device__ __forceinline__ float dotq(uint4 q, const float* p) {
    float4 a = *(const float4*)p;
    float4 b = *(const float4*)(p + 4);
    return lo16(q.x) * a.x + hi16(q.x) * a.y + lo16(q.y) * a.z + hi16(q.y) * a.w
         + lo16(q.z) * b.x + hi16(q.z) * b.y + lo16(q.w) * b.z + hi16(q.w) * b.w;
}

// ---------- dtype-world detector (proven) ----------
__global__ void k_detect(const void* __restrict__ emb, int* __restrict__ flag) {
    __shared__ int s;
    if (threadIdx.x == 0) s = 0;
    __syncthreads();
    const u16* p = (const u16*)emb;
    int bad = 0;
    for (int i = threadIdx.x; i < 8192; i += 256) {
        float v = b2f(p[i]);
        if (!(fabsf(v) < 1e4f)) bad = 1;
    }
    if (bad) s = 1;
    __syncthreads();
    if (threadIdx.x == 0) *flag = s;
}

// ---------- weight canonicalizer ----------
__global__ void k_conv(const void* __restrict__ src, u16* __restrict__ dst, int n,
                       const int* __restrict__ flag) {
    int i = blockIdx.x * 256 + threadIdx.x;
    if (i >= n) return;
    if (*flag) dst[i] = f2b(((const float*)src)[i]);
    else       dst[i] = ((const u16*)src)[i];
}

// ---------- Watt transpose ----------
__global__ void k_wattT(const void* __restrict__ src, u16* __restrict__ dst,
                        const int* __restrict__ flag) {
    int c = blockIdx.x;   // 0..511
    int r = threadIdx.x;  // 0..255
    u16 v;
    if (*flag) v = f2b(((const float*)src)[(size_t)r * 512 + c]);
    else       v = ((const u16*)src)[(size_t)r * 512 + c];
    dst[(size_t)c * 256 + r] = v;
}

// ---------- embedding gather -> internal bf16 ----------
__global__ void k_embed(const int* __restrict__ tok, const void* __restrict__ emb,
                        u16* __restrict__ out, const int* __restrict__ flag) {
    int row = blockIdx.x;
    int e = threadIdx.x;
    int v = tok[row];
    u16 r;
    if (*flag) r = f2b(((const float*)emb)[(size_t)v * 256 + e]);
    else       r = ((const u16*)emb)[(size_t)v * 256 + e];
    out[(size_t)row * 256 + e] = r;
}

// ---------- generic GEMM: C[m][n] = sum_k A[m][k]*B[n][k] (+bias[n]) ----------
template <typename TA, typename TC>
__global__ __launch_bounds__(256) void k_gemm_nt(
    const TA* __restrict__ A, int lda,
    const u16* __restrict__ B, int ldb,
    const u16* __restrict__ bias,
    TC* __restrict__ C, int ldc,
    int M, int N, int K) {
    __shared__ float As[32][68];
    __shared__ float Bs[32][68];
    const int bm = blockIdx.y * 64, bn = blockIdx.x * 64;
    const int tid = threadIdx.x;
    const int tm = (tid & 15) * 4, tn = (tid >> 4) * 4;
    float acc[4][4] = {};
    const int ml = tid >> 2, kl = (tid & 3) * 8;
    for (int k0 = 0; k0 < K; k0 += 32) {
        {
            float v[8];
            if (bm + ml < M) {
                const TA* ap = A + (size_t)(bm + ml) * lda + (k0 + kl);
#pragma unroll
                for (int i = 0; i < 8; i++) v[i] = cvtf(ap[i]);
            } else {
#pragma unroll
                for (int i = 0; i < 8; i++) v[i] = 0.f;
            }
#pragma unroll
            for (int i = 0; i < 8; i++) As[kl + i][ml] = v[i];
        }
        {
            float v[8];
            if (bn + ml < N) {
                const u16* bp = B + (size_t)(bn + ml) * ldb + (k0 + kl);
#pragma unroll
                for (int i = 0; i < 8; i++) v[i] = b2f(bp[i]);
            } else {
#pragma unroll
                for (int i = 0; i < 8; i++) v[i] = 0.f;
            }
#pragma unroll
            for (int i = 0; i < 8; i++) Bs[kl + i][ml] = v[i];
        }
        __syncthreads();
#pragma unroll
        for (int k = 0; k < 32; k++) {
            float4 av = *(const float4*)&As[k][tm];
            float4 bv = *(const float4*)&Bs[k][tn];
            acc[0][0] += av.x * bv.x; acc[0][1] += av.x * bv.y; acc[0][2] += av.x * bv.z; acc[0][3] += av.x * bv.w;
            acc[1][0] += av.y * bv.x; acc[1][1] += av.y * bv.y; acc[1][2] += av.y * bv.z; acc[1][3] += av.y * bv.w;
            acc[2][0] += av.z * bv.x; acc[2][1] += av.z * bv.y; acc[2][2] += av.z * bv.z; acc[2][3] += av.z * bv.w;
            acc[3][0] += av.w * bv.x; acc[3][1] += av.w * bv.y; acc[3][2] += av.w * bv.z; acc[3][3] += av.w * bv.w;
        }
        __syncthreads();
    }
#pragma unroll
    for (int i = 0; i < 4; i++) {
        int m = bm + tm + i;
        if (m >= M) continue;
#pragma unroll
        for (int j = 0; j < 4; j++) {
            int n = bn + tn + j;
            float v = acc[i][j];
            if (bias) v += b2f(bias[n]);
            storef(&C[(size_t)m * ldc + n], v);
        }
    }
}

// ---------- batched transpose: enc[b][s][d] -> encT[b][d][s] ----------
__global__ __launch_bounds__(256) void k_transpose(const u16* __restrict__ enc,
                                                   u16* __restrict__ encT) {
    __shared__ u16 tile[64][65];
    const int b = blockIdx.z, st = blockIdx.x * 64, dt = blockIdx.y * 64;
    const int tx = threadIdx.x & 63, r0 = (threadIdx.x >> 6) * 16;
    const u16* src = enc + ((size_t)b * 512 + st) * 512 + dt;
#pragma unroll
    for (int r = 0; r < 16; r++)
        tile[r0 + r][tx] = src[(size_t)(r0 + r) * 512 + tx];
    __syncthreads();
    u16* dst = encT + ((size_t)b * 512 + dt) * 512 + st;
#pragma unroll
    for (int r = 0; r < 16; r++)
        dst[(size_t)(r0 + r) * 512 + tx] = tile[tx][r0 + r];
}

// ---------- persistent encoder: 64 blocks (dir*32+b) x 512 threads, 512 steps ----------
// __launch_bounds__(512,2): VGPR cap 256 so u32 w[128] stays IN REGISTERS
// (at the default 128-VGPR cap the compiler spilled it to scratch -> 8.6 GB/dispatch).
__global__ __launch_bounds__(512, 2) void k_enc_persist(
    const u16* __restrict__ Xf, const u16* __restrict__ Xb,
    const u16* __restrict__ Whh_f, const u16* __restrict__ Whh_b,
    u16* __restrict__ enc, float* __restrict__ hFB) {
    const int d = blockIdx.x >> 5, b = blockIdx.x & 31;
    const int t = threadIdx.x;
    const u16* W = d ? Whh_b : Whh_f;
    u32 w[128];
    {
        const uint4* p0 = (const uint4*)(W + (size_t)t * 256);
#pragma unroll
        for (int i = 0; i < 32; i++) *(uint4*)&w[i * 4] = p0[i];
    }
    const uint4* wst = (const uint4*)(W + (size_t)(t + 512) * 256);  // 32 uint4
    __shared__ float hs[256];
    __shared__ float af[256], ao[256];
    float c = 0.f;
    if (t < 256) hs[t] = 0.f;
    __syncthreads();
    const u16* Xd = d ? Xb : Xf;
    for (int step = 0; step < 512; step++) {
        const int pos = d ? (511 - step) : step;
        const u16* xp = Xd + ((size_t)pos * 32 + b) * 1024;
        float a0 = b2f(xp[t]), a1 = b2f(xp[t + 512]);
#pragma unroll
        for (int i = 0; i < 32; i++)
            a0 += dotq(*(const uint4*)&w[i * 4], &hs[i * 8]);
#pragma unroll 8
        for (int i = 0; i < 32; i++)
            a1 += dotq(wst[i], &hs[i * 8]);
        if (t >= 256) { af[t - 256] = a0; ao[t - 256] = a1; }
        __syncthreads();
        if (t < 256) {
            float ig = sigf(a0), gg = tanhf(a1);
            float fg = sigf(af[t]), og = sigf(ao[t]);
            c = fg * c + ig * gg;
            float h = og * tanhf(c);
            hs[t] = h;
            enc[((size_t)b * 512 + pos) * 512 + (size_t)d * 256 + t] = f2b(h);
        }
        __syncthreads();
    }
    if (t < 256) hFB[(size_t)b * 512 + (size_t)d * 256 + t] = hs[t];
}

// ---------- persistent decoder: 32 blocks (b) x 512 threads, 127 steps ----------
// Same VGPR-cap fix: w[128] must be register-resident.
__global__ __launch_bounds__(512, 2) void k_dec_persist(
    const u16* __restrict__ Ypart,
    const u16* __restrict__ Whh_d, const u16* __restrict__ Wih_d,
    const u16* __restrict__ WattT, const u16* __restrict__ Wcomb,
    const u16* __restrict__ enc, const u16* __restrict__ encT,
    const float* __restrict__ ht0, const float* __restrict__ ct0,
    float* __restrict__ hid) {
    const int b = blockIdx.x;
    const int t = threadIdx.x;
    u32 w[128];
    {
        const uint4* p0 = (const uint4*)(Whh_d + (size_t)t * 256);
#pragma unroll
        for (int i = 0; i < 32; i++) *(uint4*)&w[i * 4] = p0[i];
    }
    const uint4* wst = (const uint4*)(Whh_d + (size_t)(t + 512) * 256);   // 32 uint4
    const uint4* wo0 = (const uint4*)(Wih_d + (size_t)t * 512 + 256);     // 32 uint4
    const uint4* wo1 = (const uint4*)(Wih_d + (size_t)(t + 512) * 512 + 256);
    __shared__ float hs[256], os[256];
    __shared__ float af[256], ao2[256];
    __shared__ float g[512], ev[512], cx[512];
    __shared__ float red[12];
    float c = 0.f;
    if (t < 256) {
        hs[t] = ht0[(size_t)b * 256 + t];
        os[t] = 0.f;
        c = ct0[(size_t)b * 256 + t];
    }
    __syncthreads();
    for (int s = 0; s < 127; s++) {
        // ---- LSTM gates: rows t (reg) and t+512 (streamed); o-part streamed ----
        const u16* yp = Ypart + ((size_t)s * 32 + b) * 1024;
        float a0 = b2f(yp[t]), a1 = b2f(yp[t + 512]);
#pragma unroll
        for (int i = 0; i < 32; i++)
            a0 += dotq(*(const uint4*)&w[i * 4], &hs[i * 8]);
#pragma unroll 8
        for (int i = 0; i < 32; i++)
            a1 += dotq(wst[i], &hs[i * 8]);
#pragma unroll 8
        for (int i = 0; i < 32; i++) {
            a0 += dotq(wo0[i], &os[i * 8]);
            a1 += dotq(wo1[i], &os[i * 8]);
        }
        if (t >= 256) { af[t - 256] = a0; ao2[t - 256] = a1; }
        __syncthreads();
        if (t < 256) {
            float ig = sigf(a0), gg = tanhf(a1);
            float fg = sigf(af[t]), og = sigf(ao2[t]);
            c = fg * c + ig * gg;
            float h = og * tanhf(c);
            hs[t] = h;
        }
        __syncthreads();
        // ---- B: g[t] = WattT[t] . h ----
        {
            const uint4* wt = (const uint4*)(WattT + (size_t)t * 256);
            float a = 0.f;
#pragma unroll 8
            for (int i = 0; i < 32; i++)
                a += dotq(wt[i], &hs[i * 8]);
            g[t] = a;
        }
        __syncthreads();
        // ---- C: e[t] = enc[b][t][:] . g ----
        float e_own;
        {
            const uint4* er = (const uint4*)(enc + ((size_t)b * 512 + t) * 512);
            float a = 0.f;
#pragma unroll 8
            for (int i = 0; i < 64; i++)
                a += dotq(er[i], &g[i * 8]);
            e_own = a;
        }
        // ---- softmax over 512 ----
        {
            float m = e_own;
            for (int off = 32; off; off >>= 1) m = fmaxf(m, __shfl_down(m, off));
            if ((t & 63) == 0) red[t >> 6] = m;
        }
        __syncthreads();
        if (t == 0) {
            float mm = red[0];
#pragma unroll
            for (int i = 1; i < 8; i++) mm = fmaxf(mm, red[i]);
            red[8] = mm;
        }
        __syncthreads();
        {
            float p = expf(e_own - red[8]);
            ev[t] = p;
            float ss = p;
            for (int off = 32; off; off >>= 1) ss += __shfl_down(ss, off);
            if ((t & 63) == 0) red[t >> 6] = ss;
        }
        __syncthreads();
        if (t == 0) {
            float s2 = 0.f;
#pragma unroll
            for (int i = 0; i < 8; i++) s2 += red[i];
            red[9] = 1.f / s2;
        }
        __syncthreads();
        // ---- D: ctx[t] = inv * encT[b][t][:] . ev ----
        {
            const uint4* er = (const uint4*)(encT + ((size_t)b * 512 + t) * 512);
            float a = 0.f;
#pragma unroll 8
            for (int i = 0; i < 64; i++)
                a += dotq(er[i], &ev[i * 8]);
            cx[t] = a * red[9];
        }
        __syncthreads();
        // ---- E: o_t partial sums (2 threads per output j) ----
        {
            const int j = t & 255;
            float a = 0.f;
            if (t < 256) {
                const uint4* wc = (const uint4*)(Wcomb + (size_t)j * 768);
#pragma unroll 8
                for (int i = 0; i < 32; i++)
                    a += dotq(wc[i], &hs[i * 8]);
#pragma unroll 8
                for (int i = 32; i < 48; i++)
                    a += dotq(wc[i], &cx[i * 8 - 256]);
            } else {
                const uint4* wc = (const uint4*)(Wcomb + (size_t)j * 768 + 384);
#pragma unroll 8
                for (int i = 0; i < 48; i++)
                    a += dotq(wc[i], &cx[128 + i * 8]);
            }
            g[t] = a;
        }
        __syncthreads();
        if (t < 256) {
            float o = tanhf(g[t] + g[t + 256]);
            os[t] = o;
            hid[((size_t)s * 32 + b) * 256 + t] = o;
        }
        __syncthreads();
    }
}

// ---------- logit at target index ----------
__global__ __launch_bounds__(256) void k_lidx(
    const int* __restrict__ target, const float* __restrict__ hid,
    const void* __restrict__ WvocV, float* __restrict__ lidx,
    const int* __restrict__ flag) {
    int p = blockIdx.x * 4 + (threadIdx.x >> 6);
    if (p >= 127 * 32) return;
    int lane = threadIdx.x & 63;
    int t = p >> 5, b = p & 31;
    int idx = target[(t + 1) * 32 + b];
    const float* h = hid + (size_t)p * 256;
    const bool f32w = (*flag != 0);
    float a = 0.f;
#pragma unroll
    for (int i = 0; i < 4; i++) {
        int k = lane * 4 + i;
        float wv = f32w ? ((const float*)WvocV)[(size_t)idx * 256 + k]
                        : b2f(((const u16*)WvocV)[(size_t)idx * 256 + k]);
        a += h[k] * wv;
    }
    for (int off = 32; off; off >>= 1) a += __shfl_down(a, off);
    if (lane == 0) lidx[p] = a;
}

// ---------- fused vocab GEMM + sum(exp(logit)) ----------
__global__ __launch_bounds__(256) void k_sumexp(
    const float* __restrict__ hid, const void* __restrict__ WvocV,
    float* __restrict__ psum, const int* __restrict__ flag) {
    const int t = blockIdx.y;
    const int cb = blockIdx.x * 128;
    const int tid = threadIdx.x;
    const bool f32w = (*flag != 0);
    __shared__ float Hsh[32][260];
    __shared__ float Wsh[32][132];
    __shared__ float red[32][33];
    {
        int r = tid >> 3, kb = (tid & 7) * 32;
        const float4* hp4 = (const float4*)(hid + ((size_t)t * 32 + r) * 256 + kb);
        float4* dst = (float4*)&Hsh[r][kb];
#pragma unroll
        for (int i = 0; i < 8; i++) dst[i] = hp4[i];
    }
    const int rt = tid >> 5, ct = tid & 31;
    float acc[4][4] = {};
    for (int kc = 0; kc < 8; kc++) {
        __syncthreads();
        {
            int c = tid >> 1, half = tid & 1;
            int k0 = half * 16;
            float w[16];
            if (f32w) {
                const float4* wf = (const float4*)((const float*)WvocV + (size_t)(cb + c) * 256 + kc * 32 + half * 16);
                float4 a0 = wf[0], a1 = wf[1], a2 = wf[2], a3 = wf[3];
                w[0] = a0.x; w[1] = a0.y; w[2] = a0.z; w[3] = a0.w;
                w[4] = a1.x; w[5] = a1.y; w[6] = a1.z; w[7] = a1.w;
                w[8] = a2.x; w[9] = a2.y; w[10] = a2.z; w[11] = a2.w;
                w[12] = a3.x; w[13] = a3.y; w[14] = a3.z; w[15] = a3.w;
            } else {
                const uint4* w4 = (const uint4*)((const u16*)WvocV + (size_t)(cb + c) * 256 + kc * 32 + half * 16);
                uint4 q0 = w4[0], q1 = w4[1];
                w[0] = lo16(q0.x); w[1] = hi16(q0.x); w[2] = lo16(q0.y); w[3] = hi16(q0.y);
                w[4] = lo16(q0.z); w[5] = hi16(q0.z); w[6] = lo16(q0.w); w[7] = hi16(q0.w);
                w[8] = lo16(q1.x); w[9] = hi16(q1.x); w[10] = lo16(q1.y); w[11] = hi16(q1.y);
                w[12] = lo16(q1.z); w[13] = hi16(q1.z); w[14] = lo16(q1.w); w[15] = hi16(q1.w);
            }
#pragma unroll
            for (int i = 0; i < 16; i++) Wsh[k0 + i][c] = w[i];
        }
        __syncthreads();
#pragma unroll
        for (int k = 0; k < 32; k++) {
            float4 bv = *(const float4*)&Wsh[k][ct * 4];
            float a0 = Hsh[rt * 4 + 0][kc * 32 + k];
            float a1 = Hsh[rt * 4 + 1][kc * 32 + k];
            float a2 = Hsh[rt * 4 + 2][kc * 32 + k];
            float a3 = Hsh[rt * 4 + 3][kc * 32 + k];
            acc[0][0] += a0 * bv.x; acc[0][1] += a0 * bv.y; acc[0][2] += a0 * bv.z; acc[0][3] += a0 * bv.w;
            acc[1][0] += a1 * bv.x; acc[1][1] += a1 * bv.y; acc[1][2] += a1 * bv.z; acc[1][3] += a1 * bv.w;
            acc[2][0] += a2 * bv.x; acc[2][1] += a2 * bv.y; acc[2][2] += a2 * bv.z; acc[2][3] += a2 * bv.w;
            acc[3][0] += a3 * bv.x; acc[3][1] += a3 * bv.y; acc[3][2] += a3 * bv.z; acc[3][3] += a3 * bv.w;
        }
    }
#pragma unroll
    for (int i = 0; i < 4; i++) {
        float s = expf(acc[i][0]) + expf(acc[i][1]) + expf(acc[i][2]) + expf(acc[i][3]);
        red[rt * 4 + i][ct] = s;
    }
    __syncthreads();
    if (tid < 32) {
        float s = 0.f;
#pragma unroll 8
        for (int c = 0; c < 32; c++) s += red[tid][c];
        atomicAdd(&psum[(size_t)t * 32 + tid], s);
    }
}

// ---------- final scores ----------
__global__ void k_scores(const int* __restrict__ target, const float* __restrict__ lidx,
                         const float* __restrict__ psum, void* __restrict__ outv,
                         const int* __restrict__ flag) {
    int b = threadIdx.x;
    if (b >= 32) return;
    float acc = 0.f;
    for (int t = 0; t < 127; t++) {
        int idx = target[(t + 1) * 32 + b];
        if (idx != 0) {
            int row = t * 32 + b;
            acc += lidx[row] - logf(psum[row]);
        }
    }
    if (*flag) ((float*)outv)[b] = acc;
    else       ((u16*)outv)[b] = f2b(acc);
}

extern "C" void kernel_launch(void* const* d_in, const int* in_sizes, int n_in,
                              void* d_out, int out_size, void* d_ws, size_t ws_size,
                              hipStream_t stream) {
    const int* source = (const int*)d_in[0];
    const int* target = (const int*)d_in[1];
    const void* src_emb = d_in[2];
    const void* tgt_emb = d_in[3];
    const void* Wih_f = d_in[4];
    const void* Whh_f = d_in[5];
    const void* b_f = d_in[6];
    const void* Wih_b = d_in[7];
    const void* Whh_b = d_in[8];
    const void* b_b = d_in[9];
    const void* Wih_d = d_in[10];
    const void* Whh_d = d_in[11];
    const void* b_d = d_in[12];
    const void* Wh = d_in[13];
    const void* Wc = d_in[14];
    const void* Watt = d_in[15];
    const void* Wcomb = d_in[16];
    const void* Wvoc = d_in[17];

    // ---- workspace layout: [flag pad][f32 buffers][u16 buffers] ----
    int* flag = (int*)d_ws;
    float* fw = (float*)d_ws;
    size_t off = 64;
    float* hid = fw + off;    off += (size_t)127 * 32 * 256;
    float* hFB = fw + off;    off += (size_t)32 * 512;
    float* ht0 = fw + off;    off += (size_t)32 * 256;
    float* ct0 = fw + off;    off += (size_t)32 * 256;
    float* lidx = fw + off;   off += 4096;
    float* psum = fw + off;   off += 4096;
    u16* ub = (u16*)(fw + off);
    size_t uo = 0;
    u16* X = ub + uo;       uo += (size_t)512 * 32 * 256;
    u16* Yemb = ub + uo;    uo += (size_t)127 * 32 * 256;
    u16* Xf = ub + uo;      uo += (size_t)512 * 32 * 1024;
    u16* Xb = ub + uo;      uo += (size_t)512 * 32 * 1024;
    u16* Ypart = ub + uo;   uo += (size_t)127 * 32 * 1024;
    u16* enc_p = ub + uo;   uo += (size_t)32 * 512 * 512;
    u16* encT = ub + uo;    uo += (size_t)32 * 512 * 512;
    u16* WattT = ub + uo;   uo += 131072;
    u16* cWih_f = ub + uo;  uo += 262144;
    u16* cWhh_f = ub + uo;  uo += 262144;
    u16* cb_f = ub + uo;    uo += 1024;
    u16* cWih_b = ub + uo;  uo += 262144;
    u16* cWhh_b = ub + uo;  uo += 262144;
    u16* cb_b = ub + uo;    uo += 1024;
    u16* cWih_d = ub + uo;  uo += 524288;
    u16* cWhh_d = ub + uo;  uo += 262144;
    u16* cb_d = ub + uo;    uo += 1024;
    u16* cWh = ub + uo;     uo += 131072;
    u16* cWc = ub + uo;     uo += 131072;
    u16* cWcomb = ub + uo;  uo += 196608;
    size_t needed = off * 4 + uo * 2;
    if (ws_size < needed) return;

    // 0. detect dtype world, canonicalize weights
    k_detect<<<1, 256, 0, stream>>>(src_emb, flag);
    auto conv = [&](const void* s, u16* d, int n) {
        k_conv<<<(n + 255) / 256, 256, 0, stream>>>(s, d, n, flag);
    };
    conv(Wih_f, cWih_f, 262144);  conv(Whh_f, cWhh_f, 262144);  conv(b_f, cb_f, 1024);
    conv(Wih_b, cWih_b, 262144);  conv(Whh_b, cWhh_b, 262144);  conv(b_b, cb_b, 1024);
    conv(Wih_d, cWih_d, 524288);  conv(Whh_d, cWhh_d, 262144);  conv(b_d, cb_d, 1024);
    conv(Wh, cWh, 131072);        conv(Wc, cWc, 131072);
    conv(Wcomb, cWcomb, 196608);
    k_wattT<<<512, 256, 0, stream>>>(Watt, WattT, flag);

    // 1. embed source
    k_embed<<<512 * 32, 256, 0, stream>>>(source, src_emb, X, flag);
    // 2. x-part gate preactivations, both directions (bf16 out)
    k_gemm_nt<u16, u16><<<dim3(16, 256), 256, 0, stream>>>(X, 256, cWih_f, 256, cb_f, Xf, 1024, 16384, 1024, 256);
    k_gemm_nt<u16, u16><<<dim3(16, 256), 256, 0, stream>>>(X, 256, cWih_b, 256, cb_b, Xb, 1024, 16384, 1024, 256);
    // 3. persistent encoder (fwd+bwd, 512 steps, 1 launch) -> enc
    k_enc_persist<<<64, 512, 0, stream>>>(Xf, Xb, cWhh_f, cWhh_b, enc_p, hFB);
    // 3b. batched transpose enc -> encT
    k_transpose<<<dim3(8, 8, 32), 256, 0, stream>>>(enc_p, encT);
    // 4. initial decoder state
    k_gemm_nt<float, float><<<dim3(4, 1), 256, 0, stream>>>(hFB, 512, cWh, 512, (const u16*)nullptr, ht0, 256, 32, 256, 512);
    k_gemm_nt<float, float><<<dim3(4, 1), 256, 0, stream>>>(hFB, 512, cWc, 512, (const u16*)nullptr, ct0, 256, 32, 256, 512);
    // 5. embed target + decoder y-part preactivations (bf16 out)
    k_embed<<<127 * 32, 256, 0, stream>>>(target, tgt_emb, Yemb, flag);
    k_gemm_nt<u16, u16><<<dim3(16, 64), 256, 0, stream>>>(Yemb, 256, cWih_d, 512, cb_d, Ypart, 1024, 4064, 1024, 256);
    // 6. persistent decoder (127 steps with attention, 1 launch)
    k_dec_persist<<<32, 512, 0, stream>>>(Ypart, cWhh_d, cWih_d, WattT, cWcomb, enc_p, encT, ht0, ct0, hid);
    // 7. scores
    hipMemsetAsync(psum, 0, 4096 * sizeof(float), stream);
    k_lidx<<<(127 * 32 + 3) / 4, 256, 0, stream>>>(target, hid, Wvoc, lidx, flag);
    k_sumexp<<<dim3(250, 127), 256, 0, stream>>>(hid, Wvoc, psum, flag);
    k_scores<<<1, 64, 0, stream>>>(target, lidx, psum, d_out, flag);
}

// Round 9
// 19415.598 us; speedup vs baseline: 3.0905x; 3.0905x over previous
//
#include <hip/hip_runtime.h>
#include <hip/hip_bf16.h>
#include <math.h>

typedef unsigned int u32;
typedef unsigned short u16;

// ---------- bf16 helpers ----------
__device__ __forceinline__ float bfbits(u32 hi) { union { u32 u; float f; } v; v.u = hi; return v.f; }
__device__ __forceinline__ float lo16(u32 p) { return bfbits(p << 16); }
__device__ __forceinline__ float hi16(u32 p) { return bfbits(p & 0xffff0000u); }
__device__ __forceinline__ float b2f(u16 x) { return bfbits(((u32)x) << 16); }
__device__ __forceinline__ u16 f2b(float f) {
    union { float f; u32 u; } v; v.f = f;
    u32 u = v.u;
    u32 r = (u + 0x7fffu + ((u >> 16) & 1u)) >> 16;  // RNE
    return (u16)r;
}
__device__ __forceinline__ float cvtf(float x) { return x; }
__device__ __forceinline__ float cvtf(u16 x) { return b2f(x); }
__device__ __forceinline__ void storef(float* p, float v) { *p = v; }
__device__ __forceinline__ void storef(u16* p, float v) { *p = f2b(v); }
__device__ __forceinline__ float sigf(float x) { return 1.f / (1.f + expf(-x)); }
// dot of one uint4 (8 packed bf16) against 8 floats at p (LDS)
__device__ __forceinline__ float dotq(uint4 q, const float* p) {
    float4 a = *(const float4*)p;
    float4 b = *(const float4*)(p + 4);
    return lo16(q.x) * a.x + hi16(q.x) * a.y + lo16(q.y) * a.z + hi16(q.y) * a.w
         + lo16(q.z) * b.x + hi16(q.z) * b.y + lo16(q.w) * b.z + hi16(q.w) * b.w;
}

// ---------- dtype-world detector (proven) ----------
__global__ void k_detect(const void* __restrict__ emb, int* __restrict__ flag) {
    __shared__ int s;
    if (threadIdx.x == 0) s = 0;
    __syncthreads();
    const u16* p = (const u16*)emb;
    int bad = 0;
    for (int i = threadIdx.x; i < 8192; i += 256) {
        float v = b2f(p[i]);
        if (!(fabsf(v) < 1e4f)) bad = 1;
    }
    if (bad) s = 1;
    __syncthreads();
    if (threadIdx.x == 0) *flag = s;
}

// ---------- weight canonicalizer ----------
__global__ void k_conv(const void* __restrict__ src, u16* __restrict__ dst, int n,
                       const int* __restrict__ flag) {
    int i = blockIdx.x * 256 + threadIdx.x;
    if (i >= n) return;
    if (*flag) dst[i] = f2b(((const float*)src)[i]);
    else       dst[i] = ((const u16*)src)[i];
}

// ---------- Watt transpose ----------
__global__ void k_wattT(const void* __restrict__ src, u16* __restrict__ dst,
                        const int* __restrict__ flag) {
    int c = blockIdx.x;   // 0..511
    int r = threadIdx.x;  // 0..255
    u16 v;
    if (*flag) v = f2b(((const float*)src)[(size_t)r * 512 + c]);
    else       v = ((const u16*)src)[(size_t)r * 512 + c];
    dst[(size_t)c * 256 + r] = v;
}

// ---------- embedding gather -> internal bf16 ----------
__global__ void k_embed(const int* __restrict__ tok, const void* __restrict__ emb,
                        u16* __restrict__ out, const int* __restrict__ flag) {
    int row = blockIdx.x;
    int e = threadIdx.x;
    int v = tok[row];
    u16 r;
    if (*flag) r = f2b(((const float*)emb)[(size_t)v * 256 + e]);
    else       r = ((const u16*)emb)[(size_t)v * 256 + e];
    out[(size_t)row * 256 + e] = r;
}

// ---------- generic GEMM: C[m][n] = sum_k A[m][k]*B[n][k] (+bias[n]) ----------
template <typename TA, typename TC>
__global__ __launch_bounds__(256) void k_gemm_nt(
    const TA* __restrict__ A, int lda,
    const u16* __restrict__ B, int ldb,
    const u16* __restrict__ bias,
    TC* __restrict__ C, int ldc,
    int M, int N, int K) {
    __shared__ float As[32][68];
    __shared__ float Bs[32][68];
    const int bm = blockIdx.y * 64, bn = blockIdx.x * 64;
    const int tid = threadIdx.x;
    const int tm = (tid & 15) * 4, tn = (tid >> 4) * 4;
    float acc[4][4] = {};
    const int ml = tid >> 2, kl = (tid & 3) * 8;
    for (int k0 = 0; k0 < K; k0 += 32) {
        {
            float v[8];
            if (bm + ml < M) {
                const TA* ap = A + (size_t)(bm + ml) * lda + (k0 + kl);
#pragma unroll
                for (int i = 0; i < 8; i++) v[i] = cvtf(ap[i]);
            } else {
#pragma unroll
                for (int i = 0; i < 8; i++) v[i] = 0.f;
            }
#pragma unroll
            for (int i = 0; i < 8; i++) As[kl + i][ml] = v[i];
        }
        {
            float v[8];
            if (bn + ml < N) {
                const u16* bp = B + (size_t)(bn + ml) * ldb + (k0 + kl);
#pragma unroll
                for (int i = 0; i < 8; i++) v[i] = b2f(bp[i]);
            } else {
#pragma unroll
                for (int i = 0; i < 8; i++) v[i] = 0.f;
            }
#pragma unroll
            for (int i = 0; i < 8; i++) Bs[kl + i][ml] = v[i];
        }
        __syncthreads();
#pragma unroll
        for (int k = 0; k < 32; k++) {
            float4 av = *(const float4*)&As[k][tm];
            float4 bv = *(const float4*)&Bs[k][tn];
            acc[0][0] += av.x * bv.x; acc[0][1] += av.x * bv.y; acc[0][2] += av.x * bv.z; acc[0][3] += av.x * bv.w;
            acc[1][0] += av.y * bv.x; acc[1][1] += av.y * bv.y; acc[1][2] += av.y * bv.z; acc[1][3] += av.y * bv.w;
            acc[2][0] += av.z * bv.x; acc[2][1] += av.z * bv.y; acc[2][2] += av.z * bv.z; acc[2][3] += av.z * bv.w;
            acc[3][0] += av.w * bv.x; acc[3][1] += av.w * bv.y; acc[3][2] += av.w * bv.z; acc[3][3] += av.w * bv.w;
        }
        __syncthreads();
    }
#pragma unroll
    for (int i = 0; i < 4; i++) {
        int m = bm + tm + i;
        if (m >= M) continue;
#pragma unroll
        for (int j = 0; j < 4; j++) {
            int n = bn + tn + j;
            float v = acc[i][j];
            if (bias) v += b2f(bias[n]);
            storef(&C[(size_t)m * ldc + n], v);
        }
    }
}

// ---------- batched transpose: enc[b][s][d] -> encT[b][d][s] ----------
__global__ __launch_bounds__(256) void k_transpose(const u16* __restrict__ enc,
                                                   u16* __restrict__ encT) {
    __shared__ u16 tile[64][65];
    const int b = blockIdx.z, st = blockIdx.x * 64, dt = blockIdx.y * 64;
    const int tx = threadIdx.x & 63, r0 = (threadIdx.x >> 6) * 16;
    const u16* src = enc + ((size_t)b * 512 + st) * 512 + dt;
#pragma unroll
    for (int r = 0; r < 16; r++)
        tile[r0 + r][tx] = src[(size_t)(r0 + r) * 512 + tx];
    __syncthreads();
    u16* dst = encT + ((size_t)b * 512 + dt) * 512 + st;
#pragma unroll
    for (int r = 0; r < 16; r++)
        dst[(size_t)(r0 + r) * 512 + tx] = tile[tx][r0 + r];
}

// ---------- persistent encoder: 64 blocks (dir*32+b) x 512 threads, 512 steps ----------
// ALL weight rows streamed from L2 via uint4 (no per-thread arrays -> no scratch
// spill; rounds 5-8 lost 8.6 GB/dispatch to spilled w[128] re-reads).
// Thread t: gate-rows t and t+512 of Whh.
__global__ __launch_bounds__(512) void k_enc_persist(
    const u16* __restrict__ Xf, const u16* __restrict__ Xb,
    const u16* __restrict__ Whh_f, const u16* __restrict__ Whh_b,
    u16* __restrict__ enc, float* __restrict__ hFB) {
    const int d = blockIdx.x >> 5, b = blockIdx.x & 31;
    const int t = threadIdx.x;
    const u16* W = d ? Whh_b : Whh_f;
    const uint4* wr0 = (const uint4*)(W + (size_t)t * 256);         // 32 uint4
    const uint4* wr1 = (const uint4*)(W + (size_t)(t + 512) * 256); // 32 uint4
    __shared__ float hs[256];
    __shared__ float af[256], ao[256];
    float c = 0.f;
    if (t < 256) hs[t] = 0.f;
    __syncthreads();
    const u16* Xd = d ? Xb : Xf;
    for (int step = 0; step < 512; step++) {
        const int pos = d ? (511 - step) : step;
        const u16* xp = Xd + ((size_t)pos * 32 + b) * 1024;
        float a0 = b2f(xp[t]), a1 = b2f(xp[t + 512]);
#pragma unroll 8
        for (int i = 0; i < 32; i++) {
            a0 += dotq(wr0[i], &hs[i * 8]);
            a1 += dotq(wr1[i], &hs[i * 8]);
        }
        if (t >= 256) { af[t - 256] = a0; ao[t - 256] = a1; }
        __syncthreads();
        if (t < 256) {
            float ig = sigf(a0), gg = tanhf(a1);
            float fg = sigf(af[t]), og = sigf(ao[t]);
            c = fg * c + ig * gg;
            float h = og * tanhf(c);
            hs[t] = h;
            enc[((size_t)b * 512 + pos) * 512 + (size_t)d * 256 + t] = f2b(h);
        }
        __syncthreads();
    }
    if (t < 256) hFB[(size_t)b * 512 + (size_t)d * 256 + t] = hs[t];
}

// ---------- persistent decoder: 32 blocks (b) x 512 threads, 127 steps ----------
// All weight/enc reads streamed from L2/L3 via uint4; no per-thread arrays.
__global__ __launch_bounds__(512) void k_dec_persist(
    const u16* __restrict__ Ypart,
    const u16* __restrict__ Whh_d, const u16* __restrict__ Wih_d,
    const u16* __restrict__ WattT, const u16* __restrict__ Wcomb,
    const u16* __restrict__ enc, const u16* __restrict__ encT,
    const float* __restrict__ ht0, const float* __restrict__ ct0,
    float* __restrict__ hid) {
    const int b = blockIdx.x;
    const int t = threadIdx.x;
    const uint4* wr0 = (const uint4*)(Whh_d + (size_t)t * 256);          // 32 uint4
    const uint4* wr1 = (const uint4*)(Whh_d + (size_t)(t + 512) * 256);  // 32 uint4
    const uint4* wo0 = (const uint4*)(Wih_d + (size_t)t * 512 + 256);    // 32 uint4
    const uint4* wo1 = (const uint4*)(Wih_d + (size_t)(t + 512) * 512 + 256);
    __shared__ float hs[256], os[256];
    __shared__ float af[256], ao2[256];
    __shared__ float g[512], ev[512], cx[512];
    __shared__ float red[12];
    float c = 0.f;
    if (t < 256) {
        hs[t] = ht0[(size_t)b * 256 + t];
        os[t] = 0.f;
        c = ct0[(size_t)b * 256 + t];
    }
    __syncthreads();
    for (int s = 0; s < 127; s++) {
        // ---- LSTM gates: rows t and t+512, h-part + o-part, all streamed ----
        const u16* yp = Ypart + ((size_t)s * 32 + b) * 1024;
        float a0 = b2f(yp[t]), a1 = b2f(yp[t + 512]);
#pragma unroll 8
        for (int i = 0; i < 32; i++) {
            a0 += dotq(wr0[i], &hs[i * 8]);
            a1 += dotq(wr1[i], &hs[i * 8]);
        }
#pragma unroll 8
        for (int i = 0; i < 32; i++) {
            a0 += dotq(wo0[i], &os[i * 8]);
            a1 += dotq(wo1[i], &os[i * 8]);
        }
        if (t >= 256) { af[t - 256] = a0; ao2[t - 256] = a1; }
        __syncthreads();
        if (t < 256) {
            float ig = sigf(a0), gg = tanhf(a1);
            float fg = sigf(af[t]), og = sigf(ao2[t]);
            c = fg * c + ig * gg;
            float h = og * tanhf(c);
            hs[t] = h;
        }
        __syncthreads();
        // ---- B: g[t] = WattT[t] . h ----
        {
            const uint4* wt = (const uint4*)(WattT + (size_t)t * 256);
            float a = 0.f;
#pragma unroll 8
            for (int i = 0; i < 32; i++)
                a += dotq(wt[i], &hs[i * 8]);
            g[t] = a;
        }
        __syncthreads();
        // ---- C: e[t] = enc[b][t][:] . g ----
        float e_own;
        {
            const uint4* er = (const uint4*)(enc + ((size_t)b * 512 + t) * 512);
            float a = 0.f;
#pragma unroll 8
            for (int i = 0; i < 64; i++)
                a += dotq(er[i], &g[i * 8]);
            e_own = a;
        }
        // ---- softmax over 512 ----
        {
            float m = e_own;
            for (int off = 32; off; off >>= 1) m = fmaxf(m, __shfl_down(m, off));
            if ((t & 63) == 0) red[t >> 6] = m;
        }
        __syncthreads();
        if (t == 0) {
            float mm = red[0];
#pragma unroll
            for (int i = 1; i < 8; i++) mm = fmaxf(mm, red[i]);
            red[8] = mm;
        }
        __syncthreads();
        {
            float p = expf(e_own - red[8]);
            ev[t] = p;
            float ss = p;
            for (int off = 32; off; off >>= 1) ss += __shfl_down(ss, off);
            if ((t & 63) == 0) red[t >> 6] = ss;
        }
        __syncthreads();
        if (t == 0) {
            float s2 = 0.f;
#pragma unroll
            for (int i = 0; i < 8; i++) s2 += red[i];
            red[9] = 1.f / s2;
        }
        __syncthreads();
        // ---- D: ctx[t] = inv * encT[b][t][:] . ev ----
        {
            const uint4* er = (const uint4*)(encT + ((size_t)b * 512 + t) * 512);
            float a = 0.f;
#pragma unroll 8
            for (int i = 0; i < 64; i++)
                a += dotq(er[i], &ev[i * 8]);
            cx[t] = a * red[9];
        }
        __syncthreads();
        // ---- E: o_t partial sums (2 threads per output j) ----
        {
            const int j = t & 255;
            float a = 0.f;
            if (t < 256) {
                const uint4* wc = (const uint4*)(Wcomb + (size_t)j * 768);
#pragma unroll 8
                for (int i = 0; i < 32; i++)
                    a += dotq(wc[i], &hs[i * 8]);
#pragma unroll 8
                for (int i = 32; i < 48; i++)
                    a += dotq(wc[i], &cx[i * 8 - 256]);
            } else {
                const uint4* wc = (const uint4*)(Wcomb + (size_t)j * 768 + 384);
#pragma unroll 8
                for (int i = 0; i < 48; i++)
                    a += dotq(wc[i], &cx[128 + i * 8]);
            }
            g[t] = a;
        }
        __syncthreads();
        if (t < 256) {
            float o = tanhf(g[t] + g[t + 256]);
            os[t] = o;
            hid[((size_t)s * 32 + b) * 256 + t] = o;
        }
        __syncthreads();
    }
}

// ---------- logit at target index ----------
__global__ __launch_bounds__(256) void k_lidx(
    const int* __restrict__ target, const float* __restrict__ hid,
    const void* __restrict__ WvocV, float* __restrict__ lidx,
    const int* __restrict__ flag) {
    int p = blockIdx.x * 4 + (threadIdx.x >> 6);
    if (p >= 127 * 32) return;
    int lane = threadIdx.x & 63;
    int t = p >> 5, b = p & 31;
    int idx = target[(t + 1) * 32 + b];
    const float* h = hid + (size_t)p * 256;
    const bool f32w = (*flag != 0);
    float a = 0.f;
#pragma unroll
    for (int i = 0; i < 4; i++) {
        int k = lane * 4 + i;
        float wv = f32w ? ((const float*)WvocV)[(size_t)idx * 256 + k]
                        : b2f(((const u16*)WvocV)[(size_t)idx * 256 + k]);
        a += h[k] * wv;
    }
    for (int off = 32; off; off >>= 1) a += __shfl_down(a, off);
    if (lane == 0) lidx[p] = a;
}

// ---------- fused vocab GEMM + sum(exp(logit)) ----------
__global__ __launch_bounds__(256) void k_sumexp(
    const float* __restrict__ hid, const void* __restrict__ WvocV,
    float* __restrict__ psum, const int* __restrict__ flag) {
    const int t = blockIdx.y;
    const int cb = blockIdx.x * 128;
    const int tid = threadIdx.x;
    const bool f32w = (*flag != 0);
    __shared__ float Hsh[32][260];
    __shared__ float Wsh[32][132];
    __shared__ float red[32][33];
    {
        int r = tid >> 3, kb = (tid & 7) * 32;
        const float4* hp4 = (const float4*)(hid + ((size_t)t * 32 + r) * 256 + kb);
        float4* dst = (float4*)&Hsh[r][kb];
#pragma unroll
        for (int i = 0; i < 8; i++) dst[i] = hp4[i];
    }
    const int rt = tid >> 5, ct = tid & 31;
    float acc[4][4] = {};
    for (int kc = 0; kc < 8; kc++) {
        __syncthreads();
        {
            int c = tid >> 1, half = tid & 1;
            int k0 = half * 16;
            float w[16];
            if (f32w) {
                const float4* wf = (const float4*)((const float*)WvocV + (size_t)(cb + c) * 256 + kc * 32 + half * 16);
                float4 a0 = wf[0], a1 = wf[1], a2 = wf[2], a3 = wf[3];
                w[0] = a0.x; w[1] = a0.y; w[2] = a0.z; w[3] = a0.w;
                w[4] = a1.x; w[5] = a1.y; w[6] = a1.z; w[7] = a1.w;
                w[8] = a2.x; w[9] = a2.y; w[10] = a2.z; w[11] = a2.w;
                w[12] = a3.x; w[13] = a3.y; w[14] = a3.z; w[15] = a3.w;
            } else {
                const uint4* w4 = (const uint4*)((const u16*)WvocV + (size_t)(cb + c) * 256 + kc * 32 + half * 16);
                uint4 q0 = w4[0], q1 = w4[1];
                w[0] = lo16(q0.x); w[1] = hi16(q0.x); w[2] = lo16(q0.y); w[3] = hi16(q0.y);
                w[4] = lo16(q0.z); w[5] = hi16(q0.z); w[6] = lo16(q0.w); w[7] = hi16(q0.w);
                w[8] = lo16(q1.x); w[9] = hi16(q1.x); w[10] = lo16(q1.y); w[11] = hi16(q1.y);
                w[12] = lo16(q1.z); w[13] = hi16(q1.z); w[14] = lo16(q1.w); w[15] = hi16(q1.w);
            }
#pragma unroll
            for (int i = 0; i < 16; i++) Wsh[k0 + i][c] = w[i];
        }
        __syncthreads();
#pragma unroll
        for (int k = 0; k < 32; k++) {
            float4 bv = *(const float4*)&Wsh[k][ct * 4];
            float a0 = Hsh[rt * 4 + 0][kc * 32 + k];
            float a1 = Hsh[rt * 4 + 1][kc * 32 + k];
            float a2 = Hsh[rt * 4 + 2][kc * 32 + k];
            float a3 = Hsh[rt * 4 + 3][kc * 32 + k];
            acc[0][0] += a0 * bv.x; acc[0][1] += a0 * bv.y; acc[0][2] += a0 * bv.z; acc[0][3] += a0 * bv.w;
            acc[1][0] += a1 * bv.x; acc[1][1] += a1 * bv.y; acc[1][2] += a1 * bv.z; acc[1][3] += a1 * bv.w;
            acc[2][0] += a2 * bv.x; acc[2][1] += a2 * bv.y; acc[2][2] += a2 * bv.z; acc[2][3] += a2 * bv.w;
            acc[3][0] += a3 * bv.x; acc[3][1] += a3 * bv.y; acc[3][2] += a3 * bv.z; acc[3][3] += a3 * bv.w;
        }
    }
#pragma unroll
    for (int i = 0; i < 4; i++) {
        float s = expf(acc[i][0]) + expf(acc[i][1]) + expf(acc[i][2]) + expf(acc[i][3]);
        red[rt * 4 + i][ct] = s;
    }
    __syncthreads();
    if (tid < 32) {
        float s = 0.f;
#pragma unroll 8
        for (int c = 0; c < 32; c++) s += red[tid][c];
        atomicAdd(&psum[(size_t)t * 32 + tid], s);
    }
}

// ---------- final scores ----------
__global__ void k_scores(const int* __restrict__ target, const float* __restrict__ lidx,
                         const float* __restrict__ psum, void* __restrict__ outv,
                         const int* __restrict__ flag) {
    int b = threadIdx.x;
    if (b >= 32) return;
    float acc = 0.f;
    for (int t = 0; t < 127; t++) {
        int idx = target[(t + 1) * 32 + b];
        if (idx != 0) {
            int row = t * 32 + b;
            acc += lidx[row] - logf(psum[row]);
        }
    }
    if (*flag) ((float*)outv)[b] = acc;
    else       ((u16*)outv)[b] = f2b(acc);
}

extern "C" void kernel_launch(void* const* d_in, const int* in_sizes, int n_in,
                              void* d_out, int out_size, void* d_ws, size_t ws_size,
                              hipStream_t stream) {
    const int* source = (const int*)d_in[0];
    const int* target = (const int*)d_in[1];
    const void* src_emb = d_in[2];
    const void* tgt_emb = d_in[3];
    const void* Wih_f = d_in[4];
    const void* Whh_f = d_in[5];
    const void* b_f = d_in[6];
    const void* Wih_b = d_in[7];
    const void* Whh_b = d_in[8];
    const void* b_b = d_in[9];
    const void* Wih_d = d_in[10];
    const void* Whh_d = d_in[11];
    const void* b_d = d_in[12];
    const void* Wh = d_in[13];
    const void* Wc = d_in[14];
    const void* Watt = d_in[15];
    const void* Wcomb = d_in[16];
    const void* Wvoc = d_in[17];

    // ---- workspace layout: [flag pad][f32 buffers][u16 buffers] ----
    int* flag = (int*)d_ws;
    float* fw = (float*)d_ws;
    size_t off = 64;
    float* hid = fw + off;    off += (size_t)127 * 32 * 256;
    float* hFB = fw + off;    off += (size_t)32 * 512;
    float* ht0 = fw + off;    off += (size_t)32 * 256;
    float* ct0 = fw + off;    off += (size_t)32 * 256;
    float* lidx = fw + off;   off += 4096;
    float* psum = fw + off;   off += 4096;
    u16* ub = (u16*)(fw + off);
    size_t uo = 0;
    u16* X = ub + uo;       uo += (size_t)512 * 32 * 256;
    u16* Yemb = ub + uo;    uo += (size_t)127 * 32 * 256;
    u16* Xf = ub + uo;      uo += (size_t)512 * 32 * 1024;
    u16* Xb = ub + uo;      uo += (size_t)512 * 32 * 1024;
    u16* Ypart = ub + uo;   uo += (size_t)127 * 32 * 1024;
    u16* enc_p = ub + uo;   uo += (size_t)32 * 512 * 512;
    u16* encT = ub + uo;    uo += (size_t)32 * 512 * 512;
    u16* WattT = ub + uo;   uo += 131072;
    u16* cWih_f = ub + uo;  uo += 262144;
    u16* cWhh_f = ub + uo;  uo += 262144;
    u16* cb_f = ub + uo;    uo += 1024;
    u16* cWih_b = ub + uo;  uo += 262144;
    u16* cWhh_b = ub + uo;  uo += 262144;
    u16* cb_b = ub + uo;    uo += 1024;
    u16* cWih_d = ub + uo;  uo += 524288;
    u16* cWhh_d = ub + uo;  uo += 262144;
    u16* cb_d = ub + uo;    uo += 1024;
    u16* cWh = ub + uo;     uo += 131072;
    u16* cWc = ub + uo;     uo += 131072;
    u16* cWcomb = ub + uo;  uo += 196608;
    size_t needed = off * 4 + uo * 2;
    if (ws_size < needed) return;

    // 0. detect dtype world, canonicalize weights
    k_detect<<<1, 256, 0, stream>>>(src_emb, flag);
    auto conv = [&](const void* s, u16* d, int n) {
        k_conv<<<(n + 255) / 256, 256, 0, stream>>>(s, d, n, flag);
    };
    conv(Wih_f, cWih_f, 262144);  conv(Whh_f, cWhh_f, 262144);  conv(b_f, cb_f, 1024);
    conv(Wih_b, cWih_b, 262144);  conv(Whh_b, cWhh_b, 262144);  conv(b_b, cb_b, 1024);
    conv(Wih_d, cWih_d, 524288);  conv(Whh_d, cWhh_d, 262144);  conv(b_d, cb_d, 1024);
    conv(Wh, cWh, 131072);        conv(Wc, cWc, 131072);
    conv(Wcomb, cWcomb, 196608);
    k_wattT<<<512, 256, 0, stream>>>(Watt, WattT, flag);

    // 1. embed source
    k_embed<<<512 * 32, 256, 0, stream>>>(source, src_emb, X, flag);
    // 2. x-part gate preactivations, both directions (bf16 out)
    k_gemm_nt<u16, u16><<<dim3(16, 256), 256, 0, stream>>>(X, 256, cWih_f, 256, cb_f, Xf, 1024, 16384, 1024, 256);
    k_gemm_nt<u16, u16><<<dim3(16, 256), 256, 0, stream>>>(X, 256, cWih_b, 256, cb_b, Xb, 1024, 16384, 1024, 256);
    // 3. persistent encoder (fwd+bwd, 512 steps, 1 launch) -> enc
    k_enc_persist<<<64, 512, 0, stream>>>(Xf, Xb, cWhh_f, cWhh_b, enc_p, hFB);
    // 3b. batched transpose enc -> encT
    k_transpose<<<dim3(8, 8, 32), 256, 0, stream>>>(enc_p, encT);
    // 4. initial decoder state
    k_gemm_nt<float, float><<<dim3(4, 1), 256, 0, stream>>>(hFB, 512, cWh, 512, (const u16*)nullptr, ht0, 256, 32, 256, 512);
    k_gemm_nt<float, float><<<dim3(4, 1), 256, 0, stream>>>(hFB, 512, cWc, 512, (const u16*)nullptr, ct0, 256, 32, 256, 512);
    // 5. embed target + decoder y-part preactivations (bf16 out)
    k_embed<<<127 * 32, 256, 0, stream>>>(target, tgt_emb, Yemb, flag);
    k_gemm_nt<u16, u16><<<dim3(16, 64), 256, 0, stream>>>(Yemb, 256, cWih_d, 512, cb_d, Ypart, 1024, 4064, 1024, 256);
    // 6. persistent decoder (127 steps with attention, 1 launch)
    k_dec_persist<<<32, 512, 0, stream>>>(Ypart, cWhh_d, cWih_d, WattT, cWcomb, enc_p, encT, ht0, ct0, hid);
    // 7. scores
    hipMemsetAsync(psum, 0, 4096 * sizeof(float), stream);
    k_lidx<<<(127 * 32 + 3) / 4, 256, 0, stream>>>(target, hid, Wvoc, lidx, flag);
    k_sumexp<<<dim3(250, 127), 256, 0, stream>>>(hid, Wvoc, psum, flag);
    k_scores<<<1, 64, 0, stream>>>(target, lidx, psum, d_out, flag);
}